// Round 3
// baseline (470.133 us; speedup 1.0000x reference)
//
#include <hip/hip_runtime.h>

typedef unsigned short u16;
typedef unsigned int u32;
typedef float f32x4 __attribute__((ext_vector_type(4)));
typedef float f32x16 __attribute__((ext_vector_type(16)));
typedef __bf16 bf16x8 __attribute__((ext_vector_type(8)));
typedef u32 u32x4 __attribute__((ext_vector_type(4)));
typedef u16 u16x4 __attribute__((ext_vector_type(4)));

#define NB 16
#define NSEQ 1024
#define NL 120
#define NLP 128
#define NC 1024
#define NH 16
#define NDH 64

__device__ __forceinline__ u16 f2bf(float f) {
  u32 u = __float_as_uint(f);
  return (u16)((u + 0x7fffu + ((u >> 16) & 1u)) >> 16);  // RNE
}

// one launch casts all five fp32 tensors to bf16; segment bounds compile-time
// (block counts: x 16384 | cond 1920 | Wq 1024 | Wkv 2048 | Wp 1024)
__global__ __launch_bounds__(256) void cast_all(
    const float* __restrict__ x, u16* __restrict__ xb,
    const float* __restrict__ cond, u16* __restrict__ condb,
    const float* __restrict__ Wq, u16* __restrict__ Wqb,
    const float* __restrict__ Wkv, u16* __restrict__ Wkvb,
    const float* __restrict__ Wp, u16* __restrict__ Wpb) {
  int bk = blockIdx.x;
  const float* src;
  u16* dst;
  if (bk < 16384) { src = x; dst = xb; }
  else if (bk < 18304) { src = cond; dst = condb; bk -= 16384; }
  else if (bk < 19328) { src = Wq; dst = Wqb; bk -= 18304; }
  else if (bk < 21376) { src = Wkv; dst = Wkvb; bk -= 19328; }
  else { src = Wp; dst = Wpb; bk -= 21376; }
  size_t i = ((size_t)bk * 256 + threadIdx.x) * 4;
  f32x4 v = *(const f32x4*)(src + i);
  u16x4 o;
  o.x = f2bf(v.x); o.y = f2bf(v.y); o.z = f2bf(v.z); o.w = f2bf(v.w);
  *(u16x4*)(dst + i) = o;
}

// C = A(MxK) * Bt(NxK)^T + bias.  Direct global->VGPR fragments, NO LDS, no
// barriers: waves drift and hide each other's L1/L2 latency. 128x128 block
// tile, 4 waves of 64x64 = 2x2 subtiles of 32x32x16 bf16 MFMA.
// bm = blockIdx % mt: same-bm blocks congruent mod 8 -> same XCD -> A-slab
// reused out of that XCD's L2 (round-robin heuristic, R1->R2 verified:
// FETCH 133->45 MB).
// 32x32 fragment layouts: A/B: m|n = lane&31, k = 8*(lane>>5) + j (j=0..7,
// K-contiguous 16B per lane). C/D: col = lane&31,
// row = (reg&3) + 8*(reg>>2) + 4*(lane>>5)  [measured m74/m101].
template <bool OUT_F32>
__global__ __launch_bounds__(256, 4) void gemm_dg(
    const u16* __restrict__ A, const u16* __restrict__ Bt,
    const float* __restrict__ bias, void* __restrict__ Cout,
    int M, int Nn, int K) {
  const int mt = M >> 7;
  const int bm = (int)blockIdx.x % mt;
  const int bn = (int)blockIdx.x / mt;
  const int m0 = bm << 7, n0 = bn << 7;
  const int tid = threadIdx.x;
  const int w = tid >> 6, lane = tid & 63;
  const int wm = (w & 1) << 6, wn = (w >> 1) << 6;
  const int l31 = lane & 31, hl = lane >> 5;

  const u16* aB = A + (size_t)(m0 + wm + l31) * K + hl * 8;
  const u16* bB = Bt + (size_t)(n0 + wn + l31) * K + hl * 8;
  const size_t rs32 = (size_t)32 * K;  // 32-row stride in u16

  f32x16 acc[2][2];
#pragma unroll
  for (int i = 0; i < 2; ++i)
#pragma unroll
    for (int j = 0; j < 2; ++j)
#pragma unroll
      for (int r = 0; r < 16; ++r) acc[i][j][r] = 0.f;

  for (int k0 = 0; k0 < K; k0 += 32) {
    bf16x8 af[2][2], bf[2][2];  // [i|j][ks]
#pragma unroll
    for (int i = 0; i < 2; ++i)
#pragma unroll
      for (int ks = 0; ks < 2; ++ks)
        af[i][ks] = *(const bf16x8*)(aB + i * rs32 + k0 + ks * 16);
#pragma unroll
    for (int j = 0; j < 2; ++j)
#pragma unroll
      for (int ks = 0; ks < 2; ++ks)
        bf[j][ks] = *(const bf16x8*)(bB + j * rs32 + k0 + ks * 16);
#pragma unroll
    for (int ks = 0; ks < 2; ++ks)
#pragma unroll
      for (int i = 0; i < 2; ++i)
#pragma unroll
        for (int j = 0; j < 2; ++j)
          acc[i][j] = __builtin_amdgcn_mfma_f32_32x32x16_bf16(af[i][ks], bf[j][ks],
                                                              acc[i][j], 0, 0, 0);
  }

#pragma unroll
  for (int j = 0; j < 2; ++j) {
    const int col = n0 + wn + j * 32 + l31;
    const float bv = bias[col];
#pragma unroll
    for (int i = 0; i < 2; ++i) {
      const int rowb = m0 + wm + i * 32 + 4 * hl;
#pragma unroll
      for (int r = 0; r < 16; ++r) {
        const int row = rowb + (r & 3) + 8 * (r >> 2);
        const float v = acc[i][j][r] + bv;
        if (OUT_F32)
          ((float*)Cout)[(size_t)row * Nn + col] = v;
        else
          ((u16*)Cout)[(size_t)row * Nn + col] = f2bf(v);
      }
    }
  }
}

// one block per (b,h,chunk-of-256-queries); K/V/mask staged in LDS once;
// 4 waves x 16 queries/iter x 4 iters
__global__ __launch_bounds__(256) void attn(
    const u16* __restrict__ Qb, const u16* __restrict__ KVb,
    const int* __restrict__ mask, u16* __restrict__ Ob) {
  __shared__ u16 Ks[NLP * NDH];    // [key][dh], keys >= NL zeroed
  __shared__ u16 Vt[NDH * NLP];    // [dh][key], keys >= NL zeroed
  __shared__ float mb[NLP];        // additive mask bias
  __shared__ u16 pb[4][16 * NLP];  // per-wave P buffer (A-layout row-major)

  const int chunk = (int)blockIdx.x & 3;
  const int h = ((int)blockIdx.x >> 2) & 15;
  const int b = (int)blockIdx.x >> 6;
  const int tid = threadIdx.x;
  const int w = tid >> 6, lane = tid & 63;
  const int quad = lane >> 4, l15 = lane & 15;
  const u16* kvbase = KVb + (size_t)b * NL * 2 * NC;

  for (int i = tid; i < NLP * 8; i += 256) {
    const int l = i >> 3, c8 = (i & 7) * 8;
    u32x4 z = {0u, 0u, 0u, 0u};
    u32x4 v = (l < NL) ? *(const u32x4*)(kvbase + (size_t)l * 2 * NC + h * NDH + c8) : z;
    *(u32x4*)&Ks[l * NDH + c8] = v;
  }
  u16* vstage = &pb[0][0];  // scratch for coalesced V rows before transpose
  for (int i = tid; i < NL * 8; i += 256) {
    const int l = i >> 3, c8 = (i & 7) * 8;
    *(u32x4*)&vstage[l * NDH + c8] =
        *(const u32x4*)(kvbase + (size_t)l * 2 * NC + NC + h * NDH + c8);
  }
  for (int i = tid; i < NLP; i += 256)
    mb[i] = (i < NL && mask[b * NL + i] != 0) ? 0.0f : -1e30f;
  __syncthreads();
  for (int i = tid; i < NDH * NLP; i += 256) {
    const int d = i >> 7, l = i & 127;
    Vt[d * NLP + l] = (l < NL) ? vstage[l * NDH + d] : (u16)0;
  }
  __syncthreads();

  const float scale = 0.125f;  // 64^-0.5
  for (int it = 0; it < 4; ++it) {
    const int q0 = chunk * 256 + it * 64 + w * 16;
    // A-frag of Q from global: A[m=lane&15][k=quad*8+j]
    const u16* qptr = Qb + (size_t)(b * NSEQ + q0 + l15) * NC + h * NDH + quad * 8;
    const bf16x8 a0 = *(const bf16x8*)qptr;
    const bf16x8 a1 = *(const bf16x8*)(qptr + 32);

    f32x4 s[8];
#pragma unroll
    for (int kt = 0; kt < 8; ++kt) {
      const u16* kb = &Ks[(kt * 16 + l15) * NDH + quad * 8];
      const bf16x8 b0 = *(const bf16x8*)kb;
      const bf16x8 b1 = *(const bf16x8*)(kb + 32);
      f32x4 t = {0.f, 0.f, 0.f, 0.f};
      t = __builtin_amdgcn_mfma_f32_16x16x32_bf16(a0, b0, t, 0, 0, 0);
      t = __builtin_amdgcn_mfma_f32_16x16x32_bf16(a1, b1, t, 0, 0, 0);
      s[kt] = t;
    }
#pragma unroll
    for (int kt = 0; kt < 8; ++kt) {
      const float mbv = mb[kt * 16 + l15];
#pragma unroll
      for (int r = 0; r < 4; ++r) s[kt][r] = s[kt][r] * scale + mbv;
    }
    // register softmax: row (quad*4+r) lives in the quad's 16 lanes across 8 subtiles
    float sum[4];
#pragma unroll
    for (int r = 0; r < 4; ++r) {
      float m = s[0][r];
#pragma unroll
      for (int kt = 1; kt < 8; ++kt) m = fmaxf(m, s[kt][r]);
      m = fmaxf(m, __shfl_xor(m, 1));
      m = fmaxf(m, __shfl_xor(m, 2));
      m = fmaxf(m, __shfl_xor(m, 4));
      m = fmaxf(m, __shfl_xor(m, 8));
      float su = 0.f;
#pragma unroll
      for (int kt = 0; kt < 8; ++kt) {
        s[kt][r] = __expf(s[kt][r] - m);
        su += s[kt][r];
      }
      su += __shfl_xor(su, 1);
      su += __shfl_xor(su, 2);
      su += __shfl_xor(su, 4);
      su += __shfl_xor(su, 8);
      sum[r] = su;
    }
#pragma unroll
    for (int r = 0; r < 4; ++r) {
      const float inv = 1.0f / sum[r];
#pragma unroll
      for (int kt = 0; kt < 8; ++kt)
        pb[w][(quad * 4 + r) * NLP + kt * 16 + l15] = f2bf(s[kt][r] * inv);
    }
    // PV: P(16x128) x V(128x64); same-wave LDS ops are in-order, no barrier needed
#pragma unroll
    for (int ntl = 0; ntl < 4; ++ntl) {
      f32x4 o = {0.f, 0.f, 0.f, 0.f};
#pragma unroll
      for (int kt = 0; kt < 4; ++kt) {
        const bf16x8 pa = *(const bf16x8*)&pb[w][l15 * NLP + kt * 32 + quad * 8];
        const bf16x8 vb = *(const bf16x8*)&Vt[(ntl * 16 + l15) * NLP + kt * 32 + quad * 8];
        o = __builtin_amdgcn_mfma_f32_16x16x32_bf16(pa, vb, o, 0, 0, 0);
      }
#pragma unroll
      for (int r = 0; r < 4; ++r)
        Ob[(size_t)(b * NSEQ + q0 + quad * 4 + r) * NC + h * NDH + ntl * 16 + l15] =
            f2bf(o[r]);
    }
  }
}

extern "C" void kernel_launch(void* const* d_in, const int* in_sizes, int n_in,
                              void* d_out, int out_size, void* d_ws, size_t ws_size,
                              hipStream_t stream) {
  const float* x = (const float*)d_in[0];
  const float* cond = (const float*)d_in[1];
  const int* mask = (const int*)d_in[2];
  const float* Wq = (const float*)d_in[3];
  const float* bq = (const float*)d_in[4];
  const float* Wkv = (const float*)d_in[5];
  const float* bkv = (const float*)d_in[6];
  const float* Wp = (const float*)d_in[7];
  const float* bp = (const float*)d_in[8];

  // workspace layout (87,293,952 B total; Ob aliases xb — x dead after Q-proj)
  char* ws = (char*)d_ws;
  u16* xb = (u16*)(ws + 0);            // 33,554,432
  u16* condb = (u16*)(ws + 33554432);  //  3,932,160
  u16* Wqb = (u16*)(ws + 37486592);    //  2,097,152
  u16* Wkvb = (u16*)(ws + 39583744);   //  4,194,304
  u16* Wpb = (u16*)(ws + 43778048);    //  2,097,152
  u16* Qb = (u16*)(ws + 45875200);     // 33,554,432
  u16* KVb = (u16*)(ws + 79429632);    //  7,864,320
  u16* Ob = xb;

  cast_all<<<22400, 256, 0, stream>>>(x, xb, cond, condb, Wq, Wqb, Wkv, Wkvb, Wp, Wpb);

  gemm_dg<false><<<128 * 8, 256, 0, stream>>>(xb, Wqb, bq, Qb, 16384, 1024, 1024);
  gemm_dg<false><<<15 * 16, 256, 0, stream>>>(condb, Wkvb, bkv, KVb, 1920, 2048, 1024);
  attn<<<1024, 256, 0, stream>>>(Qb, KVb, mask, Ob);
  gemm_dg<true><<<128 * 8, 256, 0, stream>>>(Ob, Wpb, bp, d_out, 16384, 1024, 1024);
}

// Round 4
// 373.629 us; speedup vs baseline: 1.2583x; 1.2583x over previous
//
#include <hip/hip_runtime.h>

typedef unsigned short u16;
typedef unsigned int u32;
typedef float f32x4 __attribute__((ext_vector_type(4)));
typedef float f32x16 __attribute__((ext_vector_type(16)));
typedef __bf16 bf16x8 __attribute__((ext_vector_type(8)));
typedef u32 u32x4 __attribute__((ext_vector_type(4)));
typedef u32 u32x2 __attribute__((ext_vector_type(2)));

#define NSEQ 1024
#define NL 120
#define NLP 128
#define NC 1024
#define NH 16
#define NDH 64
// padded LDS row stride in u16 (80 B = 5 x 16B chunks): b128 frag reads hit
// bank-quad (5*row + chunk) % 8 -> all 8 quads evenly (5 coprime 8) -> zero
// extra conflict cycles (R2's 64B stride hit 2 quads -> 8-way, 4.19e6 counts)
#define LDP 40

__device__ __forceinline__ u16 f2bf(float f) {
  u32 u = __float_as_uint(f);
  return (u16)((u + 0x7fffu + ((u >> 16) & 1u)) >> 16);  // RNE
}

// pack 2 fp32 -> 2 bf16 (round-half-up): 3 VALU ops for 2 values
__device__ __forceinline__ u32 pk2bf(float lo, float hi) {
  u32 a = __float_as_uint(lo) + 0x8000u;
  u32 b = __float_as_uint(hi) + 0x8000u;
  return __builtin_amdgcn_perm(b, a, 0x07060302);  // [b.hi16 : a.hi16]
}

// C = A(MxK) * Bt(NxK)^T + bias. 128x128 tile, BK=32, 4 waves of 64x64 =
// 2x2 subtiles of 32x32x16 bf16 MFMA (layouts verified R3).
// A is fp32 (A_BF16=false, cast fused into staging) or bf16. B always fp32.
// bm = blockIdx % mt: same-bm blocks congruent mod 8 -> same XCD L2 reuse
// (R1->R2 verified FETCH 133->45 MB).
// Pipeline: barrier; ds_write(staged regs); fire next global loads; barrier;
// frag reads + MFMA -> global-load latency hides under MFMA phase.
template <bool A_BF16, bool OUT_F32>
__global__ __launch_bounds__(256) void gemm(
    const void* __restrict__ Ap, const void* __restrict__ Bp,
    const float* __restrict__ bias, void* __restrict__ Cout,
    int M, int Nn, int K) {
  __shared__ u16 As[128 * LDP];
  __shared__ u16 Bs[128 * LDP];
  const int mt = M >> 7;
  const int bm = (int)blockIdx.x % mt;
  const int bn = (int)blockIdx.x / mt;
  const int m0 = bm << 7, n0 = bn << 7;
  const int tid = threadIdx.x;

  // staging address setup
  const int sr = tid >> 3, sc = tid & 7;  // fp32 path: 32 rows x 8 chunks of 16B
  const int hr = tid >> 2, hc = tid & 3;  // bf16 path: 64 rows x 4 chunks of 16B
  const float* bG = (const float*)Bp + (size_t)(n0 + sr) * K + sc * 4;
  u16* bW = &Bs[sr * LDP + sc * 4];
  const float* aGf = (const float*)Ap + (size_t)(m0 + sr) * K + sc * 4;
  u16* aWf = &As[sr * LDP + sc * 4];
  const u16* aGh = (const u16*)Ap + (size_t)(m0 + hr) * K + hc * 8;
  u16* aWh = &As[hr * LDP + hc * 8];

  // fragment read addresses (A/B operand: m|n = lane&31, k = 8*(lane>>5)+j)
  const int w = tid >> 6, lane = tid & 63;
  const int wm = (w & 1) << 6, wn = (w >> 1) << 6;
  const int l31 = lane & 31, hl = lane >> 5;
  const u16* aF = &As[(wm + l31) * LDP + hl * 8];
  const u16* bF = &Bs[(wn + l31) * LDP + hl * 8];

  f32x16 acc[2][2];
#pragma unroll
  for (int i = 0; i < 2; ++i)
#pragma unroll
    for (int j = 0; j < 2; ++j)
#pragma unroll
      for (int r = 0; r < 16; ++r) acc[i][j][r] = 0.f;

  f32x4 gb[4], gbn[4], gaf[4], gafn[4];
  u32x4 gah[2], gahn[2];

  // prologue: load k0 = 0
#pragma unroll
  for (int r = 0; r < 4; ++r) gb[r] = *(const f32x4*)(bG + (size_t)(r * 32) * K);
  if (A_BF16) {
#pragma unroll
    for (int r = 0; r < 2; ++r) gah[r] = *(const u32x4*)(aGh + (size_t)(r * 64) * K);
  } else {
#pragma unroll
    for (int r = 0; r < 4; ++r) gaf[r] = *(const f32x4*)(aGf + (size_t)(r * 32) * K);
  }

  for (int k0 = 0; k0 < K; k0 += 32) {
    __syncthreads();  // previous iter's frag reads complete
    // commit staged regs to LDS (compiler waits vmcnt here)
#pragma unroll
    for (int r = 0; r < 4; ++r) {
      u32x2 p = {pk2bf(gb[r].x, gb[r].y), pk2bf(gb[r].z, gb[r].w)};
      *(u32x2*)(bW + r * 32 * LDP) = p;
    }
    if (A_BF16) {
#pragma unroll
      for (int r = 0; r < 2; ++r) *(u32x4*)(aWh + r * 64 * LDP) = gah[r];
    } else {
#pragma unroll
      for (int r = 0; r < 4; ++r) {
        u32x2 p = {pk2bf(gaf[r].x, gaf[r].y), pk2bf(gaf[r].z, gaf[r].w)};
        *(u32x2*)(aWf + r * 32 * LDP) = p;
      }
    }
    // fire next-iter global loads (fire-and-forget; waited at next commit)
    if (k0 + 32 < K) {
      const int kn = k0 + 32;
#pragma unroll
      for (int r = 0; r < 4; ++r) gbn[r] = *(const f32x4*)(bG + (size_t)(r * 32) * K + kn);
      if (A_BF16) {
#pragma unroll
        for (int r = 0; r < 2; ++r)
          gahn[r] = *(const u32x4*)(aGh + (size_t)(r * 64) * K + kn);
      } else {
#pragma unroll
        for (int r = 0; r < 4; ++r)
          gafn[r] = *(const f32x4*)(aGf + (size_t)(r * 32) * K + kn);
      }
    }
    __syncthreads();  // staged tile visible

    bf16x8 af[2][2], bf[2][2];
#pragma unroll
    for (int i = 0; i < 2; ++i)
#pragma unroll
      for (int ks = 0; ks < 2; ++ks)
        af[i][ks] = *(const bf16x8*)(aF + i * 32 * LDP + ks * 16);
#pragma unroll
    for (int j = 0; j < 2; ++j)
#pragma unroll
      for (int ks = 0; ks < 2; ++ks)
        bf[j][ks] = *(const bf16x8*)(bF + j * 32 * LDP + ks * 16);
#pragma unroll
    for (int ks = 0; ks < 2; ++ks)
#pragma unroll
      for (int i = 0; i < 2; ++i)
#pragma unroll
        for (int j = 0; j < 2; ++j)
          acc[i][j] = __builtin_amdgcn_mfma_f32_32x32x16_bf16(af[i][ks], bf[j][ks],
                                                              acc[i][j], 0, 0, 0);
    // rotate ping-pong staging regs
#pragma unroll
    for (int r = 0; r < 4; ++r) gb[r] = gbn[r];
    if (A_BF16) {
#pragma unroll
      for (int r = 0; r < 2; ++r) gah[r] = gahn[r];
    } else {
#pragma unroll
      for (int r = 0; r < 4; ++r) gaf[r] = gafn[r];
    }
  }

  // epilogue: C/D col = lane&31, row = (r&3) + 8*(r>>2) + 4*(lane>>5)
  // 32-lane contiguous cols -> full 64B(bf16)/128B(f32) lines (fixes R2's
  // WRITE_SIZE 82->34 MB amplification)
#pragma unroll
  for (int j = 0; j < 2; ++j) {
    const int col = n0 + wn + j * 32 + l31;
    const float bv = bias[col];
#pragma unroll
    for (int i = 0; i < 2; ++i) {
      const int rowb = m0 + wm + i * 32 + 4 * hl;
#pragma unroll
      for (int r = 0; r < 16; ++r) {
        const int row = rowb + (r & 3) + 8 * (r >> 2);
        const float v = acc[i][j][r] + bv;
        if (OUT_F32)
          ((float*)Cout)[(size_t)row * Nn + col] = v;
        else
          ((u16*)Cout)[(size_t)row * Nn + col] = f2bf(v);
      }
    }
  }
}

// one block per (b,h,chunk-of-256-queries); K/V/mask staged in LDS once;
// 4 waves x 16 queries/iter x 4 iters
__global__ __launch_bounds__(256) void attn(
    const u16* __restrict__ Qb, const u16* __restrict__ KVb,
    const int* __restrict__ mask, u16* __restrict__ Ob) {
  __shared__ u16 Ks[NLP * NDH];    // [key][dh], keys >= NL zeroed
  __shared__ u16 Vt[NDH * NLP];    // [dh][key], keys >= NL zeroed
  __shared__ float mb[NLP];        // additive mask bias
  __shared__ u16 pb[4][16 * NLP];  // per-wave P buffer (A-layout row-major)

  const int chunk = (int)blockIdx.x & 3;
  const int h = ((int)blockIdx.x >> 2) & 15;
  const int b = (int)blockIdx.x >> 6;
  const int tid = threadIdx.x;
  const int w = tid >> 6, lane = tid & 63;
  const int quad = lane >> 4, l15 = lane & 15;
  const u16* kvbase = KVb + (size_t)b * NL * 2 * NC;

  for (int i = tid; i < NLP * 8; i += 256) {
    const int l = i >> 3, c8 = (i & 7) * 8;
    u32x4 z = {0u, 0u, 0u, 0u};
    u32x4 v = (l < NL) ? *(const u32x4*)(kvbase + (size_t)l * 2 * NC + h * NDH + c8) : z;
    *(u32x4*)&Ks[l * NDH + c8] = v;
  }
  u16* vstage = &pb[0][0];  // scratch for coalesced V rows before transpose
  for (int i = tid; i < NL * 8; i += 256) {
    const int l = i >> 3, c8 = (i & 7) * 8;
    *(u32x4*)&vstage[l * NDH + c8] =
        *(const u32x4*)(kvbase + (size_t)l * 2 * NC + NC + h * NDH + c8);
  }
  for (int i = tid; i < NLP; i += 256)
    mb[i] = (i < NL && mask[b * NL + i] != 0) ? 0.0f : -1e30f;
  __syncthreads();
  for (int i = tid; i < NDH * NLP; i += 256) {
    const int d = i >> 7, l = i & 127;
    Vt[d * NLP + l] = (l < NL) ? vstage[l * NDH + d] : (u16)0;
  }
  __syncthreads();

  const float scale = 0.125f;  // 64^-0.5
  for (int it = 0; it < 4; ++it) {
    const int q0 = chunk * 256 + it * 64 + w * 16;
    // A-frag of Q from global: A[m=lane&15][k=quad*8+j]
    const u16* qptr = Qb + (size_t)(b * NSEQ + q0 + l15) * NC + h * NDH + quad * 8;
    const bf16x8 a0 = *(const bf16x8*)qptr;
    const bf16x8 a1 = *(const bf16x8*)(qptr + 32);

    f32x4 s[8];
#pragma unroll
    for (int kt = 0; kt < 8; ++kt) {
      const u16* kb = &Ks[(kt * 16 + l15) * NDH + quad * 8];
      const bf16x8 b0 = *(const bf16x8*)kb;
      const bf16x8 b1 = *(const bf16x8*)(kb + 32);
      f32x4 t = {0.f, 0.f, 0.f, 0.f};
      t = __builtin_amdgcn_mfma_f32_16x16x32_bf16(a0, b0, t, 0, 0, 0);
      t = __builtin_amdgcn_mfma_f32_16x16x32_bf16(a1, b1, t, 0, 0, 0);
      s[kt] = t;
    }
#pragma unroll
    for (int kt = 0; kt < 8; ++kt) {
      const float mbv = mb[kt * 16 + l15];
#pragma unroll
      for (int r = 0; r < 4; ++r) s[kt][r] = s[kt][r] * scale + mbv;
    }
    // register softmax: row (quad*4+r) lives in the quad's 16 lanes across 8 subtiles
    float sum[4];
#pragma unroll
    for (int r = 0; r < 4; ++r) {
      float m = s[0][r];
#pragma unroll
      for (int kt = 1; kt < 8; ++kt) m = fmaxf(m, s[kt][r]);
      m = fmaxf(m, __shfl_xor(m, 1));
      m = fmaxf(m, __shfl_xor(m, 2));
      m = fmaxf(m, __shfl_xor(m, 4));
      m = fmaxf(m, __shfl_xor(m, 8));
      float su = 0.f;
#pragma unroll
      for (int kt = 0; kt < 8; ++kt) {
        s[kt][r] = __expf(s[kt][r] - m);
        su += s[kt][r];
      }
      su += __shfl_xor(su, 1);
      su += __shfl_xor(su, 2);
      su += __shfl_xor(su, 4);
      su += __shfl_xor(su, 8);
      sum[r] = su;
    }
#pragma unroll
    for (int r = 0; r < 4; ++r) {
      const float inv = 1.0f / sum[r];
#pragma unroll
      for (int kt = 0; kt < 8; ++kt)
        pb[w][(quad * 4 + r) * NLP + kt * 16 + l15] = f2bf(s[kt][r] * inv);
    }
    // PV: P(16x128) x V(128x64); same-wave LDS ops are in-order, no barrier needed
#pragma unroll
    for (int ntl = 0; ntl < 4; ++ntl) {
      f32x4 o = {0.f, 0.f, 0.f, 0.f};
#pragma unroll
      for (int kt = 0; kt < 4; ++kt) {
        const bf16x8 pa = *(const bf16x8*)&pb[w][l15 * NLP + kt * 32 + quad * 8];
        const bf16x8 vb = *(const bf16x8*)&Vt[(ntl * 16 + l15) * NLP + kt * 32 + quad * 8];
        o = __builtin_amdgcn_mfma_f32_16x16x32_bf16(pa, vb, o, 0, 0, 0);
      }
#pragma unroll
      for (int r = 0; r < 4; ++r)
        Ob[(size_t)(b * NSEQ + q0 + quad * 4 + r) * NC + h * NDH + ntl * 16 + l15] =
            f2bf(o[r]);
    }
  }
}

extern "C" void kernel_launch(void* const* d_in, const int* in_sizes, int n_in,
                              void* d_out, int out_size, void* d_ws, size_t ws_size,
                              hipStream_t stream) {
  const float* x = (const float*)d_in[0];
  const float* cond = (const float*)d_in[1];
  const int* mask = (const int*)d_in[2];
  const float* Wq = (const float*)d_in[3];
  const float* bq = (const float*)d_in[4];
  const float* Wkv = (const float*)d_in[5];
  const float* bkv = (const float*)d_in[6];
  const float* Wp = (const float*)d_in[7];
  const float* bp = (const float*)d_in[8];

  // workspace: casts are fused into GEMM staging, only bf16 activations remain
  char* ws = (char*)d_ws;
  u16* Qb = (u16*)(ws + 0);            // 33,554,432
  u16* KVb = (u16*)(ws + 33554432);    //  7,864,320
  u16* Ob = (u16*)(ws + 41418752);     // 33,554,432  (total 74,973,184)

  gemm<false, false><<<128 * 8, 256, 0, stream>>>(x, Wq, bq, Qb, 16384, 1024, 1024);
  gemm<false, false><<<15 * 16, 256, 0, stream>>>(cond, Wkv, bkv, KVb, 1920, 2048, 1024);
  attn<<<1024, 256, 0, stream>>>(Qb, KVb, mask, Ob);
  gemm<true, true><<<128 * 8, 256, 0, stream>>>(Ob, Wp, bp, d_out, 16384, 1024, 1024);
}

// Round 5
// 327.806 us; speedup vs baseline: 1.4342x; 1.1398x over previous
//
#include <hip/hip_runtime.h>

typedef unsigned short u16;
typedef unsigned int u32;
typedef float f32x4 __attribute__((ext_vector_type(4)));
typedef __bf16 bf16x8 __attribute__((ext_vector_type(8)));
typedef u32 u32x4 __attribute__((ext_vector_type(4)));
typedef u16 u16x4 __attribute__((ext_vector_type(4)));

#define NB 16
#define NSEQ 1024
#define NL 120
#define NLP 128
#define NC 1024
#define NH 16
#define NDH 64
// attn LDS row strides (u16), padded so row bank-start = 4*row (distinct per
// 8-lane phase of ds_read_b128): 72*2=144 B, 136*2=272 B; both 16B-aligned.
// Unpadded 128/256 B strides put EVERY row at bank 0 -> ~16-way conflicts.
#define KSP 72
#define VTP 136

__device__ __forceinline__ u16 f2bf(float f) {
  u32 u = __float_as_uint(f);
  return (u16)((u + 0x7fffu + ((u >> 16) & 1u)) >> 16);  // RNE
}

__device__ __forceinline__ void gld_lds16(const void* g, void* l) {
  __builtin_amdgcn_global_load_lds(
      (const __attribute__((address_space(1))) void*)g,
      (__attribute__((address_space(3))) void*)l, 16, 0, 0);
}

// one launch casts all five fp32 tensors to bf16; segment bounds compile-time
// (block counts: x 16384 | cond 1920 | Wq 1024 | Wkv 2048 | Wp 1024)
__global__ __launch_bounds__(256) void cast_all(
    const float* __restrict__ x, u16* __restrict__ xb,
    const float* __restrict__ cond, u16* __restrict__ condb,
    const float* __restrict__ Wq, u16* __restrict__ Wqb,
    const float* __restrict__ Wkv, u16* __restrict__ Wkvb,
    const float* __restrict__ Wp, u16* __restrict__ Wpb) {
  int bk = blockIdx.x;
  const float* src;
  u16* dst;
  if (bk < 16384) { src = x; dst = xb; }
  else if (bk < 18304) { src = cond; dst = condb; bk -= 16384; }
  else if (bk < 19328) { src = Wq; dst = Wqb; bk -= 18304; }
  else if (bk < 21376) { src = Wkv; dst = Wkvb; bk -= 19328; }
  else { src = Wp; dst = Wpb; bk -= 21376; }
  size_t i = ((size_t)bk * 256 + threadIdx.x) * 4;
  f32x4 v = *(const f32x4*)(src + i);
  u16x4 o;
  o.x = f2bf(v.x); o.y = f2bf(v.y); o.z = f2bf(v.z); o.w = f2bf(v.w);
  *(u16x4*)(dst + i) = o;
}

// C = A(MxK) * Bt(NxK)^T + bias; m97 structure (R2's 64us kernel) + swizzle.
// global_load_lds forces LDS dst = base + lane*16, so LDS can't be padded;
// instead each row's four 16B k-chunks are stored ROTATED by (row>>1)&3 (we
// permute the per-lane GLOBAL address; same 64B line -> coalescing intact).
// Frag read adds the same rotation: phase bank-starts {0,16,4,20,8,24,12,28}
// -> conflict-free (R2 measured 4.19e6 = 4 extra cyc per b128 without this).
template <bool OUT_F32>
__global__ __launch_bounds__(256) void gemm_bt(
    const u16* __restrict__ A, const u16* __restrict__ Bt,
    const float* __restrict__ bias, void* __restrict__ Cout,
    int M, int Nn, int K) {
  __shared__ u16 As[128 * 32];
  __shared__ u16 Bs[128 * 32];
  const int mt = M >> 7;
  const int bm = (int)blockIdx.x % mt;  // same-bm blocks -> same XCD (R2: FETCH 133->45MB)
  const int bn = (int)blockIdx.x / mt;
  const int m0 = bm << 7, n0 = bn << 7;
  const int tid = threadIdx.x;
  const int w = tid >> 6, lane = tid & 63;
  const int wm = (w & 1) << 6, wn = (w >> 1) << 6;
  const int quad = lane >> 4, l15 = lane & 15;

  f32x4 acc[4][4];
#pragma unroll
  for (int i = 0; i < 4; ++i)
#pragma unroll
    for (int j = 0; j < 4; ++j) acc[i][j] = (f32x4){0.f, 0.f, 0.f, 0.f};

  // staging: 16B/thread, 2 rounds each for A and B
  const int r0 = tid >> 2;
  // swizzled global k-chunk for this lane's fixed LDS slot (tid&3):
  const int cb = ((((tid & 3) - (r0 >> 1)) & 3)) << 3;
  const u16* aP = A + (size_t)(m0 + r0) * K + cb;
  const u16* bP = Bt + (size_t)(n0 + r0) * K + cb;
  u16* asDst = &As[r0 * 32 + ((tid & 3) << 3)];
  u16* bsDst = &Bs[r0 * 32 + ((tid & 3) << 3)];

  // frag-read chunk rotation: row = wm+i*16+l15 -> (row>>1)&3 == (l15>>1)&3
  const int sw = ((quad + (l15 >> 1)) & 3) << 3;

  for (int k0 = 0; k0 < K; k0 += 32) {
    __syncthreads();
    gld_lds16(aP + k0, asDst);
    gld_lds16(aP + (size_t)64 * K + k0, asDst + 64 * 32);
    gld_lds16(bP + k0, bsDst);
    gld_lds16(bP + (size_t)64 * K + k0, bsDst + 64 * 32);
    __syncthreads();

    bf16x8 af[4], bfr[4];
#pragma unroll
    for (int i = 0; i < 4; ++i)
      af[i] = *(const bf16x8*)&As[(wm + i * 16 + l15) * 32 + sw];
#pragma unroll
    for (int j = 0; j < 4; ++j)
      bfr[j] = *(const bf16x8*)&Bs[(wn + j * 16 + l15) * 32 + sw];
#pragma unroll
    for (int i = 0; i < 4; ++i)
#pragma unroll
      for (int j = 0; j < 4; ++j)
        acc[i][j] =
            __builtin_amdgcn_mfma_f32_16x16x32_bf16(af[i], bfr[j], acc[i][j], 0, 0, 0);
  }

  // epilogue: C/D layout col=lane&15, row=quad*4+reg  [verified m89/m91]
#pragma unroll
  for (int j = 0; j < 4; ++j) {
    const int col = n0 + wn + j * 16 + l15;
    const float bv = bias[col];
#pragma unroll
    for (int i = 0; i < 4; ++i) {
      const int row = m0 + wm + i * 16 + quad * 4;
#pragma unroll
      for (int r = 0; r < 4; ++r) {
        const float v = acc[i][j][r] + bv;
        if (OUT_F32)
          ((float*)Cout)[(size_t)(row + r) * Nn + col] = v;
        else
          ((u16*)Cout)[(size_t)(row + r) * Nn + col] = f2bf(v);
      }
    }
  }
}

// one block per (b,h,chunk-of-256-queries); K/V/mask staged in LDS once;
// 4 waves x 16 queries/iter x 4 iters. Padded strides KSP/VTP kill the
// 16-way bank conflicts of the unpadded layout.
__global__ __launch_bounds__(256) void attn(
    const u16* __restrict__ Qb, const u16* __restrict__ KVb,
    const int* __restrict__ mask, u16* __restrict__ Ob) {
  __shared__ u16 Ks[NLP * KSP];    // [key][dh], keys >= NL zeroed
  __shared__ u16 Vt[NDH * VTP];    // [dh][key], keys >= NL zeroed
  __shared__ float mb[NLP];        // additive mask bias
  __shared__ u16 pb[4][16 * VTP];  // per-wave P buffer (A-layout row-major)

  const int chunk = (int)blockIdx.x & 3;
  const int h = ((int)blockIdx.x >> 2) & 15;
  const int b = (int)blockIdx.x >> 6;
  const int tid = threadIdx.x;
  const int w = tid >> 6, lane = tid & 63;
  const int quad = lane >> 4, l15 = lane & 15;
  const u16* kvbase = KVb + (size_t)b * NL * 2 * NC;

  for (int i = tid; i < NLP * 8; i += 256) {
    const int l = i >> 3, c8 = (i & 7) * 8;
    u32x4 z = {0u, 0u, 0u, 0u};
    u32x4 v = (l < NL) ? *(const u32x4*)(kvbase + (size_t)l * 2 * NC + h * NDH + c8) : z;
    *(u32x4*)&Ks[l * KSP + c8] = v;
  }
  u16* vstage = &pb[0][0];  // scratch (spans pb, consumed before pb use)
  for (int i = tid; i < NL * 8; i += 256) {
    const int l = i >> 3, c8 = (i & 7) * 8;
    *(u32x4*)&vstage[l * NDH + c8] =
        *(const u32x4*)(kvbase + (size_t)l * 2 * NC + NC + h * NDH + c8);
  }
  for (int i = tid; i < NLP; i += 256)
    mb[i] = (i < NL && mask[b * NL + i] != 0) ? 0.0f : -1e30f;
  __syncthreads();
  for (int i = tid; i < NDH * NLP; i += 256) {
    const int d = i >> 7, l = i & 127;
    Vt[d * VTP + l] = (l < NL) ? vstage[l * NDH + d] : (u16)0;
  }
  __syncthreads();

  const float scale = 0.125f;  // 64^-0.5
  for (int it = 0; it < 4; ++it) {
    const int q0 = chunk * 256 + it * 64 + w * 16;
    // A-frag of Q from global: A[m=lane&15][k=quad*8+j]
    const u16* qptr = Qb + (size_t)(b * NSEQ + q0 + l15) * NC + h * NDH + quad * 8;
    const bf16x8 a0 = *(const bf16x8*)qptr;
    const bf16x8 a1 = *(const bf16x8*)(qptr + 32);

    f32x4 s[8];
#pragma unroll
    for (int kt = 0; kt < 8; ++kt) {
      const u16* kb = &Ks[(kt * 16 + l15) * KSP + quad * 8];
      const bf16x8 b0 = *(const bf16x8*)kb;
      const bf16x8 b1 = *(const bf16x8*)(kb + 32);
      f32x4 t = {0.f, 0.f, 0.f, 0.f};
      t = __builtin_amdgcn_mfma_f32_16x16x32_bf16(a0, b0, t, 0, 0, 0);
      t = __builtin_amdgcn_mfma_f32_16x16x32_bf16(a1, b1, t, 0, 0, 0);
      s[kt] = t;
    }
#pragma unroll
    for (int kt = 0; kt < 8; ++kt) {
      const float mbv = mb[kt * 16 + l15];
#pragma unroll
      for (int r = 0; r < 4; ++r) s[kt][r] = s[kt][r] * scale + mbv;
    }
    // register softmax: row (quad*4+r) lives in the quad's 16 lanes across 8 subtiles
    float sum[4];
#pragma unroll
    for (int r = 0; r < 4; ++r) {
      float m = s[0][r];
#pragma unroll
      for (int kt = 1; kt < 8; ++kt) m = fmaxf(m, s[kt][r]);
      m = fmaxf(m, __shfl_xor(m, 1));
      m = fmaxf(m, __shfl_xor(m, 2));
      m = fmaxf(m, __shfl_xor(m, 4));
      m = fmaxf(m, __shfl_xor(m, 8));
      float su = 0.f;
#pragma unroll
      for (int kt = 0; kt < 8; ++kt) {
        s[kt][r] = __expf(s[kt][r] - m);
        su += s[kt][r];
      }
      su += __shfl_xor(su, 1);
      su += __shfl_xor(su, 2);
      su += __shfl_xor(su, 4);
      su += __shfl_xor(su, 8);
      sum[r] = su;
    }
#pragma unroll
    for (int r = 0; r < 4; ++r) {
      const float inv = 1.0f / sum[r];
#pragma unroll
      for (int kt = 0; kt < 8; ++kt)
        pb[w][(quad * 4 + r) * VTP + kt * 16 + l15] = f2bf(s[kt][r] * inv);
    }
    // PV: P(16x128) x V(128x64); same-wave LDS ops are in-order, no barrier needed
#pragma unroll
    for (int ntl = 0; ntl < 4; ++ntl) {
      f32x4 o = {0.f, 0.f, 0.f, 0.f};
#pragma unroll
      for (int kt = 0; kt < 4; ++kt) {
        const bf16x8 pa = *(const bf16x8*)&pb[w][l15 * VTP + kt * 32 + quad * 8];
        const bf16x8 vb = *(const bf16x8*)&Vt[(ntl * 16 + l15) * VTP + kt * 32 + quad * 8];
        o = __builtin_amdgcn_mfma_f32_16x16x32_bf16(pa, vb, o, 0, 0, 0);
      }
#pragma unroll
      for (int r = 0; r < 4; ++r)
        Ob[(size_t)(b * NSEQ + q0 + quad * 4 + r) * NC + h * NDH + ntl * 16 + l15] =
            f2bf(o[r]);
    }
  }
}

extern "C" void kernel_launch(void* const* d_in, const int* in_sizes, int n_in,
                              void* d_out, int out_size, void* d_ws, size_t ws_size,
                              hipStream_t stream) {
  const float* x = (const float*)d_in[0];
  const float* cond = (const float*)d_in[1];
  const int* mask = (const int*)d_in[2];
  const float* Wq = (const float*)d_in[3];
  const float* bq = (const float*)d_in[4];
  const float* Wkv = (const float*)d_in[5];
  const float* bkv = (const float*)d_in[6];
  const float* Wp = (const float*)d_in[7];
  const float* bp = (const float*)d_in[8];

  // workspace layout (87,293,952 B total; Ob aliases xb — x dead after Q-proj)
  char* ws = (char*)d_ws;
  u16* xb = (u16*)(ws + 0);            // 33,554,432
  u16* condb = (u16*)(ws + 33554432);  //  3,932,160
  u16* Wqb = (u16*)(ws + 37486592);    //  2,097,152
  u16* Wkvb = (u16*)(ws + 39583744);   //  4,194,304
  u16* Wpb = (u16*)(ws + 43778048);    //  2,097,152
  u16* Qb = (u16*)(ws + 45875200);     // 33,554,432
  u16* KVb = (u16*)(ws + 79429632);    //  7,864,320
  u16* Ob = xb;

  cast_all<<<22400, 256, 0, stream>>>(x, xb, cond, condb, Wq, Wqb, Wkv, Wkvb, Wp, Wpb);

  gemm_bt<false><<<128 * 8, 256, 0, stream>>>(xb, Wqb, bq, Qb, 16384, 1024, 1024);
  gemm_bt<false><<<15 * 16, 256, 0, stream>>>(condb, Wkvb, bkv, KVb, 1920, 2048, 1024);
  attn<<<1024, 256, 0, stream>>>(Qb, KVb, mask, Ob);
  gemm_bt<true><<<128 * 8, 256, 0, stream>>>(Ob, Wpb, bp, d_out, 16384, 1024, 1024);
}